// Round 7
// baseline (216.258 us; speedup 1.0000x reference)
//
#include <hip/hip_runtime.h>

typedef int i32x4 __attribute__((ext_vector_type(4)));

#define QMAXF 127.0f
#define LGKM0() asm volatile("s_waitcnt lgkmcnt(0)" ::: "memory")
#define BAR()   __builtin_amdgcn_s_barrier()

// ---------------------------------------------------------------------------
// Weight quantization: one block per output row (cout). ~2 us.
// ---------------------------------------------------------------------------
__global__ __launch_bounds__(256) void quant_w_kernel(
    const float* __restrict__ w, const float* __restrict__ act_scale,
    signed char* __restrict__ qw, float* __restrict__ wscale)
{
    const int row = blockIdx.x;
    const int t   = threadIdx.x;
    const float s = act_scale[0];

    float4 v = *reinterpret_cast<const float4*>(w + (size_t)row * 1024 + t * 4);
    float a0 = v.x * s, a1 = v.y * s, a2 = v.z * s, a3 = v.w * s;
    float m = fmaxf(fmaxf(fabsf(a0), fabsf(a1)), fmaxf(fabsf(a2), fabsf(a3)));

    #pragma unroll
    for (int i = 1; i < 64; i <<= 1)
        m = fmaxf(m, __shfl_xor(m, i));

    __shared__ float wmax[4];
    if ((t & 63) == 0) wmax[t >> 6] = m;
    __syncthreads();
    m = fmaxf(fmaxf(wmax[0], wmax[1]), fmaxf(wmax[2], wmax[3]));

    const float wsc = m / QMAXF;

    int q0 = (int)rintf(a0 / wsc);
    int q1 = (int)rintf(a1 / wsc);
    int q2 = (int)rintf(a2 / wsc);
    int q3 = (int)rintf(a3 / wsc);
    int packed = (q0 & 255) | ((q1 & 255) << 8) | ((q2 & 255) << 16) | ((q3 & 255) << 24);
    reinterpret_cast<int*>(qw)[row * 256 + t] = packed;

    if (t == 0) wscale[row] = wsc;
}

// ---------------------------------------------------------------------------
// Fused quant(x)+GEMM: round-4's proven 256x256 8-phase/counted-wait skeleton;
// A-path replaced by f32 x load -> in-register quant -> swizzled ds_write.
// B: global_load_lds, pre-swizzled source slot^(row&7), linear LDS dest.
// A: ds_write_b128 at slot^(row&7) directly. Readers re-apply the XOR.
// Schedule per iter (tiles T even->buf0, T+1 odd->buf1), phases:
//  P1 LDA(0,0) LDB(0,0) XLD(T+1,h0)            | MM(0,0)
//  P2 LDB(0,1)          XLD(T+1,h1)            | MM(0,1)
//  P3 LDA(0,1) STAGE_B(T+2,h0) AQW(T+1,h0)     | MM(1,0)
//  P4          STAGE_B(T+2,h1) AQW(T+1,h1) MM(1,1)
//  P5..P8 mirror on buf1 with T+2/T+3.
// AQW's implicit vmcnt waits (in-order retire) drain exactly the older
// B-halves each half-iteration; newer B stages stay in flight (counted-wait
// effect with zero manual vmcnt). LGKM0 precedes every barrier after writes.
// ---------------------------------------------------------------------------
#define NTILES 8   // K/128

__global__ __launch_bounds__(512, 2) void gemm_fused_kernel(
    const float* __restrict__ x, const signed char* __restrict__ qw,
    const float* __restrict__ act_scale, const float* __restrict__ wscale,
    const float* __restrict__ bias, float* __restrict__ out, int M)
{
    const int K = 1024, N = 1024;
    __shared__ __align__(16) signed char As[4][16384];  // [ (kt&1)*2 + half ]
    __shared__ __align__(16) signed char Bs[4][16384];

    const int t    = threadIdx.x;
    const int lane = t & 63;
    const int w    = t >> 6;       // wave 0..7
    const int wr   = w >> 2;       // M half
    const int wc   = w & 3;        // N quarter
    const int lrow = lane & 15;
    const int ks   = lane >> 4;
    const int r8   = lane >> 3;
    const int sl   = lane & 7;
    const int ar   = t >> 2;       // A row within 128-row half
    const int ac2  = t & 3;        // 32B chunk -> global slots 2*ac2, 2*ac2+1

    const int nwg = gridDim.x;
    const int cpx = nwg >> 3;
    const int bid = blockIdx.x;
    const int swz = (bid & 7) * cpx + (bid >> 3);
    const int m0 = (swz >> 2) * 256;   // n-minor within XCD chunk: x-panel L2 reuse
    const int n0 = (swz & 3) * 256;

    const float rinv = 1.0f / act_scale[0];

    i32x4 acc[8][4] = {};
    i32x4 Ar[4][2];
    i32x4 Br[2][2][2];
    float4 X0[8], X1[8];

    auto STAGE_B = [&](int kt, int h) {
        signed char* lb = &Bs[(kt & 1) * 2 + h][0];
        #pragma unroll
        for (int j = 0; j < 2; ++j) {
            const int rowh = (j * 8 + w) * 8 + r8;        // 0..127, rowh&7==r8
            const signed char* src =
                qw + (size_t)(n0 + h * 128 + rowh) * K + kt * 128 + ((sl ^ r8) << 4);
            __builtin_amdgcn_global_load_lds(
                (const __attribute__((address_space(1))) void*)src,
                (__attribute__((address_space(3))) void*)(lb + ((j * 8 + w) * 64 + lane) * 16),
                16, 0, 0);
        }
    };
    auto XLD = [&](int kt, int h, float4 (&X)[8]) {
        const float* p = x + (size_t)(m0 + h * 128 + ar) * K + kt * 128 + ac2 * 32;
        #pragma unroll
        for (int j = 0; j < 8; ++j) X[j] = *reinterpret_cast<const float4*>(p + j * 4);
    };
    auto AQW = [&](int kt, int h, const float4 (&X)[8]) {
        int pk[8];
        #pragma unroll
        for (int c = 0; c < 8; ++c) {
            int q0 = (int)rintf(fminf(fmaxf(X[c].x * rinv, -QMAXF), QMAXF));
            int q1 = (int)rintf(fminf(fmaxf(X[c].y * rinv, -QMAXF), QMAXF));
            int q2 = (int)rintf(fminf(fmaxf(X[c].z * rinv, -QMAXF), QMAXF));
            int q3 = (int)rintf(fminf(fmaxf(X[c].w * rinv, -QMAXF), QMAXF));
            pk[c] = (q0 & 255) | ((q1 & 255) << 8) | ((q2 & 255) << 16) | ((q3 & 255) << 24);
        }
        signed char* base = &As[(kt & 1) * 2 + h][0];
        const int g0 = 2 * ac2, g1 = 2 * ac2 + 1;
        *reinterpret_cast<i32x4*>(base + ar * 128 + ((g0 ^ (ar & 7)) << 4)) =
            i32x4{pk[0], pk[1], pk[2], pk[3]};
        *reinterpret_cast<i32x4*>(base + ar * 128 + ((g1 ^ (ar & 7)) << 4)) =
            i32x4{pk[4], pk[5], pk[6], pk[7]};
    };
    auto LDA = [&](int buf, int mh) {
        const signed char* base = &As[buf * 2 + wr][0];
        #pragma unroll
        for (int mf = 0; mf < 4; ++mf) {
            const int row = mh * 64 + mf * 16 + lrow;
            #pragma unroll
            for (int kk = 0; kk < 2; ++kk) {
                const int slot = (kk * 4 + ks) ^ (lrow & 7);   // row&7 == lrow&7
                Ar[mf][kk] = *reinterpret_cast<const i32x4*>(base + row * 128 + slot * 16);
            }
        }
    };
    auto LDB = [&](int buf, int nh, i32x4 (&B)[2][2]) {
        const signed char* base = &Bs[buf * 2 + (wc >> 1)][0];
        #pragma unroll
        for (int nf = 0; nf < 2; ++nf) {
            const int row = (wc & 1) * 64 + nh * 32 + nf * 16 + lrow;
            #pragma unroll
            for (int kk = 0; kk < 2; ++kk) {
                const int slot = (kk * 4 + ks) ^ (lrow & 7);
                B[nf][kk] = *reinterpret_cast<const i32x4*>(base + row * 128 + slot * 16);
            }
        }
    };
    auto MM = [&](int mh, int nh, i32x4 (&B)[2][2]) {
        __builtin_amdgcn_s_setprio(1);
        #pragma unroll
        for (int mf = 0; mf < 4; ++mf)
            #pragma unroll
            for (int nf = 0; nf < 2; ++nf)
                #pragma unroll
                for (int kk = 0; kk < 2; ++kk)
                    acc[mh * 4 + mf][nh * 2 + nf] = __builtin_amdgcn_mfma_i32_16x16x64_i8(
                        Ar[mf][kk], B[nf][kk], acc[mh * 4 + mf][nh * 2 + nf], 0, 0, 0);
        __builtin_amdgcn_s_setprio(0);
    };

    // ---- prologue: B(0), x(0)->A(0) (implicit wait drains B(0)), B(1) ----
    STAGE_B(0, 0); STAGE_B(0, 1);
    XLD(0, 0, X0); XLD(0, 1, X1);
    AQW(0, 0, X0); AQW(0, 1, X1);
    STAGE_B(1, 0); STAGE_B(1, 1);
    LGKM0(); BAR();

    #pragma unroll
    for (int it = 0; it < NTILES / 2; ++it) {
        const int T = 2 * it;
        // ---- P1 ----
        LDA(0, 0); LDB(0, 0, Br[0]);
        XLD(T + 1, 0, X0);
        BAR(); LGKM0();
        MM(0, 0, Br[0]);
        BAR();
        // ---- P2 ----
        LDB(0, 1, Br[1]);
        XLD(T + 1, 1, X1);
        BAR(); LGKM0();
        MM(0, 1, Br[1]);
        BAR();
        // ---- P3 ----
        LDA(0, 1);
        if (T + 2 < NTILES) STAGE_B(T + 2, 0);
        AQW(T + 1, 0, X0);           // implicit vmcnt drains older B(T+1)
        LGKM0(); BAR();
        MM(1, 0, Br[0]);
        BAR();
        // ---- P4 ----
        if (T + 2 < NTILES) STAGE_B(T + 2, 1);
        AQW(T + 1, 1, X1);
        MM(1, 1, Br[1]);
        LGKM0(); BAR();
        // ---- P5 ----
        LDA(1, 0); LDB(1, 0, Br[0]);
        if (T + 2 < NTILES) XLD(T + 2, 0, X0);
        BAR(); LGKM0();
        MM(0, 0, Br[0]);
        BAR();
        // ---- P6 ----
        LDB(1, 1, Br[1]);
        if (T + 2 < NTILES) XLD(T + 2, 1, X1);
        BAR(); LGKM0();
        MM(0, 1, Br[1]);
        BAR();
        // ---- P7 ----
        LDA(1, 1);
        if (T + 3 < NTILES) STAGE_B(T + 3, 0);
        if (T + 2 < NTILES) AQW(T + 2, 0, X0);   // drains older B(T+2)
        LGKM0(); BAR();
        MM(1, 0, Br[0]);
        BAR();
        // ---- P8 ----
        if (T + 3 < NTILES) STAGE_B(T + 3, 1);
        if (T + 2 < NTILES) AQW(T + 2, 1, X1);
        MM(1, 1, Br[1]);
        LGKM0(); BAR();
    }

    // ---- epilogue: dequant + bias ----
    float wsv[4], bv[4];
    int   gnc[4];
    #pragma unroll
    for (int nf = 0; nf < 4; ++nf) {
        const int gn = n0 + wc * 64 + nf * 16 + lrow;
        gnc[nf] = gn;
        wsv[nf] = wscale[gn];
        bv[nf]  = bias[gn];
    }
    #pragma unroll
    for (int mf = 0; mf < 8; ++mf) {
        #pragma unroll
        for (int r = 0; r < 4; ++r) {
            const int gm = m0 + wr * 128 + mf * 16 + ks * 4 + r;
            float* orow = out + (size_t)gm * N;
            #pragma unroll
            for (int nf = 0; nf < 4; ++nf)
                orow[gnc[nf]] = (float)acc[mf][nf][r] * wsv[nf] + bv[nf];
        }
    }
}

// ---------------------------------------------------------------------------
extern "C" void kernel_launch(void* const* d_in, const int* in_sizes, int n_in,
                              void* d_out, int out_size, void* d_ws, size_t ws_size,
                              hipStream_t stream)
{
    const float* x         = (const float*)d_in[0];
    const float* weight    = (const float*)d_in[1];
    const float* bias      = (const float*)d_in[2];
    const float* act_scale = (const float*)d_in[3];
    float* out             = (float*)d_out;

    const int K = 1024;
    const int N = 1024;
    const int M = in_sizes[0] / K;   // 32768

    // workspace: qw (N*K int8) | wscale (N f32)
    char* wsb = (char*)d_ws;
    signed char* qw  = (signed char*)wsb;
    float*       wsc = (float*)(wsb + (size_t)N * K);

    quant_w_kernel<<<N, 256, 0, stream>>>(weight, act_scale, qw, wsc);

    const int grid = (M / 256) * (N / 256);   // 512, divisible by 8
    gemm_fused_kernel<<<grid, 512, 0, stream>>>(x, qw, act_scale, wsc, bias, out, M);
}

// Round 8
// 88.369 us; speedup vs baseline: 2.4472x; 2.4472x over previous
//
#include <hip/hip_runtime.h>

typedef int i32x4 __attribute__((ext_vector_type(4)));

#define QMAXF 127.0f
#define LGKM0() asm volatile("s_waitcnt lgkmcnt(0)" ::: "memory")
#define BAR()   __builtin_amdgcn_s_barrier()

// ---------------------------------------------------------------------------
// Weight quantization: one block per output row (cout). ~2 us. Proven R3-R7.
// ---------------------------------------------------------------------------
__global__ __launch_bounds__(256) void quant_w_kernel(
    const float* __restrict__ w, const float* __restrict__ act_scale,
    signed char* __restrict__ qw, float* __restrict__ wscale)
{
    const int row = blockIdx.x;
    const int t   = threadIdx.x;
    const float s = act_scale[0];

    float4 v = *reinterpret_cast<const float4*>(w + (size_t)row * 1024 + t * 4);
    float a0 = v.x * s, a1 = v.y * s, a2 = v.z * s, a3 = v.w * s;
    float m = fmaxf(fmaxf(fabsf(a0), fabsf(a1)), fmaxf(fabsf(a2), fabsf(a3)));

    #pragma unroll
    for (int i = 1; i < 64; i <<= 1)
        m = fmaxf(m, __shfl_xor(m, i));

    __shared__ float wmax[4];
    if ((t & 63) == 0) wmax[t >> 6] = m;
    __syncthreads();
    m = fmaxf(fmaxf(wmax[0], wmax[1]), fmaxf(wmax[2], wmax[3]));

    const float wsc = m / QMAXF;

    int q0 = (int)rintf(a0 / wsc);
    int q1 = (int)rintf(a1 / wsc);
    int q2 = (int)rintf(a2 / wsc);
    int q3 = (int)rintf(a3 / wsc);
    int packed = (q0 & 255) | ((q1 & 255) << 8) | ((q2 & 255) << 16) | ((q3 & 255) << 24);
    reinterpret_cast<int*>(qw)[row * 256 + t] = packed;

    if (t == 0) wscale[row] = wsc;
}

// ---------------------------------------------------------------------------
// Activation quantization (proven, at BW floor ~24 us)
// ---------------------------------------------------------------------------
__global__ __launch_bounds__(256) void quant_x_kernel(
    const float* __restrict__ x, const float* __restrict__ act_scale,
    signed char* __restrict__ xq)
{
    const float s = act_scale[0];
    const size_t i = ((size_t)blockIdx.x * 256 + threadIdx.x) * 4;
    float4 v = *reinterpret_cast<const float4*>(x + i);
    int q0 = (int)rintf(fminf(fmaxf(v.x / s, -QMAXF), QMAXF));
    int q1 = (int)rintf(fminf(fmaxf(v.y / s, -QMAXF), QMAXF));
    int q2 = (int)rintf(fminf(fmaxf(v.z / s, -QMAXF), QMAXF));
    int q3 = (int)rintf(fminf(fmaxf(v.w / s, -QMAXF), QMAXF));
    int packed = (q0 & 255) | ((q1 & 255) << 8) | ((q2 & 255) << 16) | ((q3 & 255) << 24);
    reinterpret_cast<int*>(xq)[i >> 2] = packed;
}

// ---------------------------------------------------------------------------
// int8 GEMM, occupancy-fixed variant of the proven R4 skeleton:
//   tile 128x256, BK=64, 8 waves (2Mx4N), per-wave 64x64 -> acc[4][4] = 64
//   regs/thread; triple-buffered LDS (A 3x8KB + B 3x16KB = 72KB) ->
//   2 blocks/CU at launch_bounds(512,4) (<=128 VGPR).
// Per K-tile T: 2 phases (8 MFMA each); stage tile T+2 into buf (T+2)%3
// while reading buf T%3; end-of-tile s_waitcnt vmcnt(3) retires T+1's 3
// loads, leaves T+2's 3 in flight (counted-vmcnt, never 0 mid-loop).
// Swizzle for 64B rows: slot ^ ((row>>1)&3)  (measured 0 conflicts R5-R7;
// fixes R3's rows{0,4,8,12} collision). Applied on pre-swizzled GLOBAL
// source (gload_lds dest linear, wave-contiguous); re-applied on ds_read.
// ---------------------------------------------------------------------------
#define NT 16   // K / 64

__global__ __launch_bounds__(512, 4) void gemm_i8_kernel(
    const signed char* __restrict__ xq, const signed char* __restrict__ qw,
    const float* __restrict__ wscale, const float* __restrict__ bias,
    float* __restrict__ out, int M)
{
    const int K = 1024, N = 1024;
    __shared__ __align__(16) signed char As[3][128 * 64];   // 24 KB
    __shared__ __align__(16) signed char Bs[3][256 * 64];   // 48 KB

    const int t    = threadIdx.x;
    const int lane = t & 63;
    const int w    = t >> 6;       // wave 0..7
    const int wr   = w >> 2;       // 0..1: M 64-row half
    const int wc   = w & 3;        // 0..3: N 64-col quarter
    const int lrow = lane & 15;
    const int ks   = lane >> 4;    // 16B K-slot 0..3

    // XCD-aware bijective swizzle; nwg = (M/128)*(N/256) = 1024, %8 == 0.
    const int nwg = gridDim.x;
    const int cpx = nwg >> 3;
    const int bid = blockIdx.x;
    const int swz = (bid & 7) * cpx + (bid >> 3);
    const int m0 = (swz >> 2) * 128;   // n-minor: A-panel L2 reuse within XCD
    const int n0 = (swz & 3) * 256;

    i32x4 acc[4][4] = {};   // 64 regs/thread

    auto STAGE_A = [&](int T, int nbuf) {
        const int r  = t >> 2;                 // 0..127
        const int sp = t & 3;
        const int gs = sp ^ ((r >> 1) & 3);
        const signed char* src = xq + (size_t)(m0 + r) * K + T * 64 + gs * 16;
        __builtin_amdgcn_global_load_lds(
            (const __attribute__((address_space(1))) void*)src,
            (__attribute__((address_space(3))) void*)(&As[nbuf][0] + t * 16), 16, 0, 0);
    };
    auto STAGE_B = [&](int T, int nbuf) {
        #pragma unroll
        for (int j = 0; j < 2; ++j) {
            const int unit = j * 512 + t;      // 0..1023
            const int r  = unit >> 2;          // 0..255
            const int sp = unit & 3;
            const int gs = sp ^ ((r >> 1) & 3);
            const signed char* src = qw + (size_t)(n0 + r) * K + T * 64 + gs * 16;
            __builtin_amdgcn_global_load_lds(
                (const __attribute__((address_space(1))) void*)src,
                (__attribute__((address_space(3))) void*)(&Bs[nbuf][0] + unit * 16), 16, 0, 0);
        }
    };
    auto LDA1 = [&](int buf, int mf) {
        const int row = wr * 64 + mf * 16 + lrow;
        const int sl  = ks ^ ((row >> 1) & 3);
        return *reinterpret_cast<const i32x4*>(&As[buf][0] + row * 64 + sl * 16);
    };
    auto LDB1 = [&](int buf, int nf) {
        const int row = wc * 64 + nf * 16 + lrow;
        const int sl  = ks ^ ((row >> 1) & 3);
        return *reinterpret_cast<const i32x4*>(&Bs[buf][0] + row * 64 + sl * 16);
    };

    // ---- prologue: stage tiles 0 and 1; retire tile 0's 3 loads ----
    STAGE_A(0, 0); STAGE_B(0, 0);
    STAGE_A(1, 1); STAGE_B(1, 1);
    asm volatile("s_waitcnt vmcnt(3)" ::: "memory");
    BAR();

    #pragma unroll
    for (int T = 0; T < NT; ++T) {
        const int buf  = T % 3;
        const int nbuf = (T + 2) % 3;
        const bool pf  = (T + 2 < NT);
        i32x4 Af[2], Bf[4];

        // ---- P1: frags (A mf0-1, B all) + stage A(T+2); MM mf0-1 ----
        Af[0] = LDA1(buf, 0); Af[1] = LDA1(buf, 1);
        #pragma unroll
        for (int nf = 0; nf < 4; ++nf) Bf[nf] = LDB1(buf, nf);
        if (pf) STAGE_A(T + 2, nbuf);
        BAR(); LGKM0();
        __builtin_amdgcn_s_setprio(1);
        #pragma unroll
        for (int mf = 0; mf < 2; ++mf)
            #pragma unroll
            for (int nf = 0; nf < 4; ++nf)
                acc[mf][nf] = __builtin_amdgcn_mfma_i32_16x16x64_i8(
                    Af[mf], Bf[nf], acc[mf][nf], 0, 0, 0);
        __builtin_amdgcn_s_setprio(0);
        BAR();

        // ---- P2: frags (A mf2-3) + stage B(T+2); MM mf2-3; counted drain ----
        Af[0] = LDA1(buf, 2); Af[1] = LDA1(buf, 3);
        if (pf) STAGE_B(T + 2, nbuf);
        BAR(); LGKM0();
        __builtin_amdgcn_s_setprio(1);
        #pragma unroll
        for (int mf = 0; mf < 2; ++mf)
            #pragma unroll
            for (int nf = 0; nf < 4; ++nf)
                acc[mf + 2][nf] = __builtin_amdgcn_mfma_i32_16x16x64_i8(
                    Af[mf], Bf[nf], acc[mf + 2][nf], 0, 0, 0);
        __builtin_amdgcn_s_setprio(0);
        if (pf)               { asm volatile("s_waitcnt vmcnt(3)" ::: "memory"); }
        else if (T + 1 < NT)  { asm volatile("s_waitcnt vmcnt(0)" ::: "memory"); }
        BAR();
    }

    // ---- epilogue: dequant + bias ----
    float wsv[4], bv[4];
    int   gnc[4];
    #pragma unroll
    for (int nf = 0; nf < 4; ++nf) {
        const int gn = n0 + wc * 64 + nf * 16 + lrow;
        gnc[nf] = gn;
        wsv[nf] = wscale[gn];
        bv[nf]  = bias[gn];
    }
    #pragma unroll
    for (int mf = 0; mf < 4; ++mf) {
        #pragma unroll
        for (int r = 0; r < 4; ++r) {
            const int gm = m0 + wr * 64 + mf * 16 + ks * 4 + r;
            float* orow = out + (size_t)gm * N;
            #pragma unroll
            for (int nf = 0; nf < 4; ++nf)
                orow[gnc[nf]] = (float)acc[mf][nf][r] * wsv[nf] + bv[nf];
        }
    }
}

// ---------------------------------------------------------------------------
extern "C" void kernel_launch(void* const* d_in, const int* in_sizes, int n_in,
                              void* d_out, int out_size, void* d_ws, size_t ws_size,
                              hipStream_t stream)
{
    const float* x         = (const float*)d_in[0];
    const float* weight    = (const float*)d_in[1];
    const float* bias      = (const float*)d_in[2];
    const float* act_scale = (const float*)d_in[3];
    float* out             = (float*)d_out;

    const int K = 1024;
    const int N = 1024;
    const int M = in_sizes[0] / K;   // 32768

    // workspace: qw (N*K int8) | wscale (N f32, padded) | xq (M*K int8)
    char* wsb = (char*)d_ws;
    signed char* qw  = (signed char*)wsb;
    float*       wsc = (float*)(wsb + (size_t)N * K);
    signed char* xq  = (signed char*)(wsb + (size_t)N * K + 4096);

    quant_w_kernel<<<N, 256, 0, stream>>>(weight, act_scale, qw, wsc);
    quant_x_kernel<<<(int)(((size_t)M * K) / 1024), 256, 0, stream>>>(x, act_scale, xq);

    const int grid = (M / 128) * (N / 256);   // 1024, divisible by 8
    gemm_i8_kernel<<<grid, 512, 0, stream>>>(xq, qw, wsc, bias, out, M);
}